// Round 14
// baseline (925.407 us; speedup 1.0000x reference)
//
#include <hip/hip_runtime.h>
#include <hip/hip_fp16.h>
#include <cstddef>

#define NN 50000
#define NE 800000
#define D 128
#define BN_EPS 1e-5f

typedef __attribute__((ext_vector_type(8))) short bf16x8;
typedef __attribute__((ext_vector_type(4))) float f32x4;

union FragU { int4 i; bf16x8 v; };

__device__ __forceinline__ unsigned short f2bf(float x) {
    unsigned u = __float_as_uint(x);
    return (unsigned short)((u + 0x7fffu + ((u >> 16) & 1u)) >> 16);  // RNE
}
__device__ __forceinline__ float bf2f(unsigned short b) {
    return __uint_as_float(((unsigned)b) << 16);
}
__device__ __forceinline__ unsigned pk2(float a, float b) {
    return (unsigned)f2bf(a) | ((unsigned)f2bf(b) << 16);
}

// mid-layer permutation: pi(16*ct + s) = 32*(ct&3) + 8*(s>>2) + 4*(ct>>2) + (s&3)
__device__ __forceinline__ int pi_perm(int ct, int s) {
    return 32 * (ct & 3) + 8 * (s >> 2) + 4 * (ct >> 2) + (s & 3);
}

// ---------------------------------------------------------------------------
// W prep, plain: fragment-linear bf16 (verified R2/R3/R5/R8)
// ---------------------------------------------------------------------------
__global__ __launch_bounds__(256) void wprep_kernel(
    const float* __restrict__ W, unsigned short* __restrict__ Wt)
{
    const int idx = blockIdx.x * 256 + threadIdx.x;   // [0, 16384)
    const int j  = idx & 7;
    const int l  = (idx >> 3) & 63;
    const int ks = (idx >> 9) & 3;
    const int ct = (idx >> 11) & 7;
    const int n  = 16 * ct + (l & 15);
    const int k  = 32 * ks + ((l >> 4) << 3) + j;
    Wt[idx] = f2bf(W[k * 128 + n]);
}

// W prep with permuted output-column (layer-1): n = pi(16ct + i)
__global__ __launch_bounds__(256) void wprep_pi_kernel(
    const float* __restrict__ W, unsigned short* __restrict__ Wt)
{
    const int idx = blockIdx.x * 256 + threadIdx.x;   // [0, 16384)
    const int j  = idx & 7;
    const int l  = (idx >> 3) & 63;
    const int ks = (idx >> 9) & 3;
    const int ct = (idx >> 11) & 7;
    const int n  = pi_perm(ct, l & 15);
    const int k  = 32 * ks + ((l >> 4) << 3) + j;
    Wt[idx] = f2bf(W[k * 128 + n]);
}

// permuted layer-1 bias: bp[16ct+s] = b[pi(16ct+s)]
__global__ void bprep_kernel(const float* __restrict__ b, float* __restrict__ bp)
{
    const int p = threadIdx.x;   // 128 threads
    bp[p] = b[pi_perm(p >> 4, p & 15)];
}

// ---------------------------------------------------------------------------
// Shuffle-free MFMA 2-layer MLP (pi-permuted, both GEMMs swapped, 64-row
// blocks — R8 structure, 345us verified) + in-kernel BN stats via m-group
// shfl reduction (lane (g,m) holds Z[m][16ct2+4g+r]; rows reduce over the
// 4 m-bits). Stats LDS reuses dead W1L after a barrier.
// MODE 0: X = e+h[src]+h[dst], rows=NE. MODE 1: X = h+agg (guarded).
// HALFX: fp16 x2 output (half write traffic).
// ---------------------------------------------------------------------------
template<int MODE, int HALFX>
__global__ __launch_bounds__(256, 2) void mlp_mfma_kernel(
    const float* __restrict__ h, const float* __restrict__ e_or_agg,
    const int* __restrict__ src, const int* __restrict__ dst,
    const unsigned short* __restrict__ Wt1, const float* __restrict__ b1p,
    const unsigned short* __restrict__ Wt2, const float* __restrict__ b2,
    void* __restrict__ x2out_v, float* __restrict__ stats)
{
    __shared__ __align__(16) unsigned short W1L[16384];   // 32 KB
    __shared__ __align__(16) unsigned short W2L[16384];   // 32 KB

    const int tid  = threadIdx.x;
    const int lane = tid & 63;
    const int w    = tid >> 6;        // 0..3
    const int g    = lane >> 4;       // 0..3
    const int m    = lane & 15;
    const long ROWS = (MODE == 0) ? NE : NN;
    const long rowg = (long)blockIdx.x * 64 + 16 * w + m;
    const long rowc = (rowg < ROWS) ? rowg : (ROWS - 1);
    const bool valid = (MODE == 0) || (rowg < ROWS);

    // ---- stage W1+W2 fragments to LDS ----
    {
        int4* d1 = (int4*)W1L;  const int4* s1 = (const int4*)Wt1;
        int4* d2 = (int4*)W2L;  const int4* s2 = (const int4*)Wt2;
#pragma unroll
        for (int i = 0; i < 8; ++i) {
            d1[tid + 256 * i] = s1[tid + 256 * i];
            d2[tid + 256 * i] = s2[tid + 256 * i];
        }
    }
    __syncthreads();
    const bf16x8* W1f = (const bf16x8*)W1L;
    const bf16x8* W2f = (const bf16x8*)W2L;

    const float *pa, *pb, *pc = nullptr;
    if (MODE == 0) {
        pa = e_or_agg + (size_t)rowc * D;
        pb = h + (size_t)src[rowc] * D;
        pc = h + (size_t)dst[rowc] * D;
    } else {
        pa = h + (size_t)rowc * D;
        pb = e_or_agg + (size_t)rowc * D;
    }

    // ---- X B-fragments direct from global, split hi/lo ----
    FragU xh[4], xl[4];
#pragma unroll
    for (int ks = 0; ks < 4; ++ks) {
        const int c = 32 * ks + 8 * g;
        const float4 aa = *(const float4*)(pa + c);
        const float4 ab = *(const float4*)(pa + c + 4);
        const float4 ba = *(const float4*)(pb + c);
        const float4 bb = *(const float4*)(pb + c + 4);
        float xs[8];
        xs[0] = aa.x + ba.x; xs[1] = aa.y + ba.y;
        xs[2] = aa.z + ba.z; xs[3] = aa.w + ba.w;
        xs[4] = ab.x + bb.x; xs[5] = ab.y + bb.y;
        xs[6] = ab.z + bb.z; xs[7] = ab.w + bb.w;
        if (MODE == 0) {
            const float4 ca = *(const float4*)(pc + c);
            const float4 cb = *(const float4*)(pc + c + 4);
            xs[0] += ca.x; xs[1] += ca.y; xs[2] += ca.z; xs[3] += ca.w;
            xs[4] += cb.x; xs[5] += cb.y; xs[6] += cb.z; xs[7] += cb.w;
        }
        const unsigned h0 = pk2(xs[0], xs[1]), h1 = pk2(xs[2], xs[3]);
        const unsigned h2 = pk2(xs[4], xs[5]), h3 = pk2(xs[6], xs[7]);
        xh[ks].i = make_int4(h0, h1, h2, h3);
        xl[ks].i = make_int4(
            pk2(xs[0] - bf2f((unsigned short)h0),
                xs[1] - bf2f((unsigned short)(h0 >> 16))),
            pk2(xs[2] - bf2f((unsigned short)h1),
                xs[3] - bf2f((unsigned short)(h1 >> 16))),
            pk2(xs[4] - bf2f((unsigned short)h2),
                xs[5] - bf2f((unsigned short)(h2 >> 16))),
            pk2(xs[6] - bf2f((unsigned short)h3),
                xs[7] - bf2f((unsigned short)(h3 >> 16))));
    }

    // ---- GEMM1 swapped+permuted: acc[ct][r] = Y[m][pi(16ct+4g+r)] ----
    f32x4 acc[8];
#pragma unroll
    for (int ct = 0; ct < 8; ++ct) acc[ct] = (f32x4){0.f, 0.f, 0.f, 0.f};
#pragma unroll
    for (int ct = 0; ct < 8; ++ct)
#pragma unroll
        for (int ks = 0; ks < 4; ++ks) {
            const bf16x8 wf = W1f[(ct * 4 + ks) * 64 + lane];
            acc[ct] = __builtin_amdgcn_mfma_f32_16x16x32_bf16(wf, xh[ks].v, acc[ct], 0, 0, 0);
            acc[ct] = __builtin_amdgcn_mfma_f32_16x16x32_bf16(wf, xl[ks].v, acc[ct], 0, 0, 0);
        }

    // ---- bias+relu, pack GEMM2 B-frags in-lane (pi makes this exact) ----
    FragU yh[4], yl[4];
#pragma unroll
    for (int ks2 = 0; ks2 < 4; ++ks2) {
        const float4 bva = *(const float4*)(b1p + 16 * ks2 + 4 * g);
        const float4 bvb = *(const float4*)(b1p + 16 * (ks2 + 4) + 4 * g);
        const float y0 = fmaxf(acc[ks2][0] + bva.x, 0.f);
        const float y1 = fmaxf(acc[ks2][1] + bva.y, 0.f);
        const float y2 = fmaxf(acc[ks2][2] + bva.z, 0.f);
        const float y3 = fmaxf(acc[ks2][3] + bva.w, 0.f);
        const float y4 = fmaxf(acc[ks2 + 4][0] + bvb.x, 0.f);
        const float y5 = fmaxf(acc[ks2 + 4][1] + bvb.y, 0.f);
        const float y6 = fmaxf(acc[ks2 + 4][2] + bvb.z, 0.f);
        const float y7 = fmaxf(acc[ks2 + 4][3] + bvb.w, 0.f);
        const unsigned u0 = pk2(y0, y1), u1 = pk2(y2, y3);
        const unsigned u2 = pk2(y4, y5), u3 = pk2(y6, y7);
        yh[ks2].i = make_int4(u0, u1, u2, u3);
        yl[ks2].i = make_int4(
            pk2(y0 - bf2f((unsigned short)u0), y1 - bf2f((unsigned short)(u0 >> 16))),
            pk2(y2 - bf2f((unsigned short)u1), y3 - bf2f((unsigned short)(u1 >> 16))),
            pk2(y4 - bf2f((unsigned short)u2), y5 - bf2f((unsigned short)(u2 >> 16))),
            pk2(y6 - bf2f((unsigned short)u3), y7 - bf2f((unsigned short)(u3 >> 16))));
    }

    // ---- GEMM2 swapped: acc2[ct2][r] = Z[m][16ct2+4g+r] ----
    f32x4 acc2[8];
#pragma unroll
    for (int ct2 = 0; ct2 < 8; ++ct2) acc2[ct2] = (f32x4){0.f, 0.f, 0.f, 0.f};
#pragma unroll
    for (int ct2 = 0; ct2 < 8; ++ct2)
#pragma unroll
        for (int ks2 = 0; ks2 < 4; ++ks2) {
            const bf16x8 wf = W2f[(ct2 * 4 + ks2) * 64 + lane];
            acc2[ct2] = __builtin_amdgcn_mfma_f32_16x16x32_bf16(wf, yh[ks2].v, acc2[ct2], 0, 0, 0);
            acc2[ct2] = __builtin_amdgcn_mfma_f32_16x16x32_bf16(wf, yl[ks2].v, acc2[ct2], 0, 0, 0);
        }

    // ---- barrier: all waves past GEMM1/GEMM2 so W1L can be reused ----
    __syncthreads();
    float* redS = (float*)W1L;          // [4][128]
    float* redQ = redS + 512;           // [4][128]

    // ---- bias + store + per-wave stats (shfl over m-bits) ----
#pragma unroll
    for (int ct2 = 0; ct2 < 8; ++ct2) {
        const float4 bv = *(const float4*)(b2 + 16 * ct2 + 4 * g);
        float z[4];
        z[0] = acc2[ct2][0] + bv.x;
        z[1] = acc2[ct2][1] + bv.y;
        z[2] = acc2[ct2][2] + bv.z;
        z[3] = acc2[ct2][3] + bv.w;
        if (valid) {
            if (HALFX) {
                __half* xp = (__half*)x2out_v + (size_t)rowg * D + 16 * ct2 + 4 * g;
                *(__half2*)(xp)     = __floats2half2_rn(z[0], z[1]);
                *(__half2*)(xp + 2) = __floats2half2_rn(z[2], z[3]);
            } else {
                float* xp = (float*)x2out_v + (size_t)rowg * D + 16 * ct2 + 4 * g;
                *(float4*)xp = make_float4(z[0], z[1], z[2], z[3]);
            }
        }
#pragma unroll
        for (int r = 0; r < 4; ++r) {
            float sv = valid ? z[r] : 0.f;
            float qv = sv * sv;
            sv += __shfl_xor(sv, 1);  qv += __shfl_xor(qv, 1);
            sv += __shfl_xor(sv, 2);  qv += __shfl_xor(qv, 2);
            sv += __shfl_xor(sv, 4);  qv += __shfl_xor(qv, 4);
            sv += __shfl_xor(sv, 8);  qv += __shfl_xor(qv, 8);
            if (m == 0) {
                const int c = 16 * ct2 + 4 * g + r;
                redS[w * 128 + c] = sv;
                redQ[w * 128 + c] = qv;
            }
        }
    }
    __syncthreads();
    if (tid < 128) {
        const float s = redS[tid] + redS[128 + tid] + redS[256 + tid] + redS[384 + tid];
        const float q = redQ[tid] + redQ[128 + tid] + redQ[256 + tid] + redQ[384 + tid];
        unsafeAtomicAdd(&stats[tid], s);
        unsafeAtomicAdd(&stats[128 + tid], q);
    }
}

// stats layout: [0:128) sum, [128:256) sumsq, [256:384) scale, [384:512) shift
__global__ void bn_finalize_kernel(float* __restrict__ stats,
                                   const float* __restrict__ gamma,
                                   const float* __restrict__ beta,
                                   float inv_count)
{
    const int c = threadIdx.x;
    if (c < D) {
        const float mu  = stats[c] * inv_count;
        const float var = stats[128 + c] * inv_count - mu * mu;
        const float sc  = rsqrtf(var + BN_EPS) * gamma[c];
        stats[256 + c] = sc;
        stats[384 + c] = beta[c] - mu * sc;
    }
}

// ---- CSR build ----
__global__ __launch_bounds__(256) void hist_kernel(
    const int* __restrict__ dst, int* __restrict__ cnt)
{
    const int i = blockIdx.x * 256 + threadIdx.x;
    if (i < NE) atomicAdd(&cnt[dst[i]], 1);
}

__global__ __launch_bounds__(1024) void scan_kernel(
    const int* __restrict__ cnt, int* __restrict__ off)
{
    __shared__ int part[1024];
    const int t = threadIdx.x;
    const int SEG = (NN + 1023) / 1024;
    const int base = t * SEG;

    int s = 0;
    for (int i = 0; i < SEG; ++i) {
        const int idx = base + i;
        if (idx < NN) s += cnt[idx];
    }
    part[t] = s;
    __syncthreads();
    for (int d = 1; d < 1024; d <<= 1) {
        int v = (t >= d) ? part[t - d] : 0;
        __syncthreads();
        part[t] += v;
        __syncthreads();
    }
    int run = (t > 0) ? part[t - 1] : 0;
    for (int i = 0; i < SEG; ++i) {
        const int idx = base + i;
        if (idx < NN) { off[idx] = run; run += cnt[idx]; }
    }
    if (t == 1023) off[NN] = part[1023];
}

__global__ __launch_bounds__(256) void csr_scatter_kernel(
    const int* __restrict__ dst, const int* __restrict__ off,
    int* __restrict__ cnt, int* __restrict__ csr)
{
    const int i = blockIdx.x * 256 + threadIdx.x;
    if (i < NE) {
        const int d = dst[i];
        const int p = atomicSub(&cnt[d], 1) - 1;
        csr[off[d] + p] = i;
    }
}

// ---------------------------------------------------------------------------
// Fused BN-apply + residual + segment-sum gather. One wave per node; each
// wave-iteration processes TWO edges (lane>>5 selects edge, (lane&31)*4
// selects 4 cols): 16B e loads, 8B x2h loads, 16B stores. Cross-half acc
// combine via shfl_xor(.,32). HALFX=1: x2 fp16; HALFX=0: f32 in-place.
// ---------------------------------------------------------------------------
template<int HALFX>
__global__ __launch_bounds__(256) void apply_gather_kernel(
    const float* __restrict__ e, const float* __restrict__ stats,
    const int* __restrict__ off, const int* __restrict__ csr,
    const void* __restrict__ x2src, float* __restrict__ eout,
    float* __restrict__ agg)
{
    const int node = blockIdx.x * 4 + (threadIdx.x >> 6);
    const int lane = threadIdx.x & 63;
    const int half = lane >> 5;          // 0: even edge, 1: odd edge
    const int c0   = (lane & 31) * 4;
    if (node >= NN) return;

    const float4 sc = *(const float4*)(stats + 256 + c0);
    const float4 sh = *(const float4*)(stats + 384 + c0);
    float4 acc = make_float4(0.f, 0.f, 0.f, 0.f);
    const int jb = off[node], je = off[node + 1];
    const int niter = (je - jb + 1) >> 1;

#pragma unroll 2
    for (int p = 0; p < niter; ++p) {
        const int j0 = jb + 2 * p + half;
        if (j0 < je) {
            const int eidx = csr[j0];
            const size_t base = (size_t)eidx * D + c0;
            float4 x;
            if (HALFX) {
                const int2 xi = *(const int2*)((const __half*)x2src + base);
                const float2 f0 = __half22float2(*(const __half2*)&xi.x);
                const float2 f1 = __half22float2(*(const __half2*)&xi.y);
                x = make_float4(f0.x, f0.y, f1.x, f1.y);
            } else {
                x = *(const float4*)(eout + base);
            }
            const float4 ev = *(const float4*)(e + base);
            float4 v;
            v.x = fmaf(x.x, sc.x, sh.x) + ev.x;
            v.y = fmaf(x.y, sc.y, sh.y) + ev.y;
            v.z = fmaf(x.z, sc.z, sh.z) + ev.z;
            v.w = fmaf(x.w, sc.w, sh.w) + ev.w;
            *(float4*)(eout + base) = v;
            acc.x += v.x; acc.y += v.y; acc.z += v.z; acc.w += v.w;
        }
    }

    // combine even/odd halves: lanes l and l+32 hold the same columns
    acc.x += __shfl_xor(acc.x, 32);
    acc.y += __shfl_xor(acc.y, 32);
    acc.z += __shfl_xor(acc.z, 32);
    acc.w += __shfl_xor(acc.w, 32);
    if (half == 0)
        *(float4*)(agg + (size_t)node * D + c0) = acc;
}

// h_new = y2*scale + shift + h (in-place over y2 in d_out)
__global__ __launch_bounds__(256) void node_apply_kernel(
    const float* __restrict__ h, const float* __restrict__ stats,
    float* __restrict__ hout)
{
    const int gid = blockIdx.x * 256 + threadIdx.x;
    const int c0  = (gid & 31) * 4;
    const size_t base = (size_t)(gid >> 5) * D + c0;

    const float4 sc = *(const float4*)(stats + 256 + c0);
    const float4 sh = *(const float4*)(stats + 384 + c0);
    const float4 x  = *(const float4*)(hout + base);
    const float4 hv = *(const float4*)(h + base);
    float4 v;
    v.x = fmaf(x.x, sc.x, sh.x) + hv.x;
    v.y = fmaf(x.y, sc.y, sh.y) + hv.y;
    v.z = fmaf(x.z, sc.z, sh.z) + hv.z;
    v.w = fmaf(x.w, sc.w, sh.w) + hv.w;
    *(float4*)(hout + base) = v;
}

extern "C" void kernel_launch(void* const* d_in, const int* in_sizes, int n_in,
                              void* d_out, int out_size, void* d_ws, size_t ws_size,
                              hipStream_t stream)
{
    const float* h   = (const float*)d_in[0];
    const float* e   = (const float*)d_in[1];
    const int*   src = (const int*)d_in[2];
    const int*   dst = (const int*)d_in[3];
    const float* Wa1 = (const float*)d_in[4];
    const float* ba1 = (const float*)d_in[5];
    const float* Wa2 = (const float*)d_in[6];
    const float* ba2 = (const float*)d_in[7];
    const float* Wb1 = (const float*)d_in[8];
    const float* bb1 = (const float*)d_in[9];
    const float* Wb2 = (const float*)d_in[10];
    const float* bb2 = (const float*)d_in[11];
    const float* ga  = (const float*)d_in[12];
    const float* bea = (const float*)d_in[13];
    const float* gb  = (const float*)d_in[14];
    const float* beb = (const float*)d_in[15];

    float* out  = (float*)d_out;
    float* hnew = out;                      // NN*D (y2 scratch, then h_new)
    float* enew = out + (size_t)NN * D;     // NE*D (e_new; x2 scratch if f32 path)

    // ws layout (float units):
    //   estats[512] | nstats[512] | icnt[NN] | ioff[NN+1] | pad3 |
    //   b1pe[128] | b1pn[128] | wtb1/wtb2/wta1/wta2 (4 x 16384 ushort) |
    //   csr[NE ints] | agg[NN*D] | x2h[NE*D halves] (only if ws_size permits)
    float* ws     = (float*)d_ws;
    float* estats = ws;
    float* nstats = ws + 512;
    int*   icnt   = (int*)(ws + 1024);
    int*   ioff   = icnt + NN;
    float* b1pe   = (float*)(ioff + NN + 1 + 3);       // 16B aligned
    float* b1pn   = b1pe + 128;
    unsigned short* wtb1 = (unsigned short*)(b1pn + 128);
    unsigned short* wtb2 = wtb1 + 16384;
    unsigned short* wta1 = wtb2 + 16384;
    unsigned short* wta2 = wta1 + 16384;
    int*    icsr = (int*)(wta2 + 16384);
    float*  agg  = (float*)(icsr + NE);
    __half* x2h  = (__half*)(agg + (size_t)NN * D);
    const size_t need_half = (size_t)((char*)(x2h + (size_t)NE * D) - (char*)d_ws);
    const bool use_half = (ws_size >= need_half);

    // zero BN stats + histogram counters
    hipMemsetAsync(d_ws, 0, (size_t)(1024 + NN) * sizeof(float), stream);

    // ---- weight/bias prep ----
    wprep_pi_kernel<<<64, 256, 0, stream>>>(Wb1, wtb1);
    wprep_kernel<<<64, 256, 0, stream>>>(Wb2, wtb2);
    wprep_pi_kernel<<<64, 256, 0, stream>>>(Wa1, wta1);
    wprep_kernel<<<64, 256, 0, stream>>>(Wa2, wta2);
    bprep_kernel<<<1, 128, 0, stream>>>(bb1, b1pe);
    bprep_kernel<<<1, 128, 0, stream>>>(ba1, b1pn);

    // ---- CSR build ----
    hist_kernel<<<(NE + 255) / 256, 256, 0, stream>>>(dst, icnt);
    scan_kernel<<<1, 1024, 0, stream>>>(icnt, ioff);
    csr_scatter_kernel<<<(NE + 255) / 256, 256, 0, stream>>>(dst, ioff, icnt, icsr);

    // ---- bond (edge) path ----
    if (use_half) {
        mlp_mfma_kernel<0, 1><<<NE / 64, 256, 0, stream>>>(
            h, e, src, dst, wtb1, b1pe, wtb2, bb2, (void*)x2h, estats);
        bn_finalize_kernel<<<1, 128, 0, stream>>>(estats, gb, beb, 1.0f / NE);
        apply_gather_kernel<1><<<(NN + 3) / 4, 256, 0, stream>>>(
            e, estats, ioff, icsr, (const void*)x2h, enew, agg);
    } else {
        mlp_mfma_kernel<0, 0><<<NE / 64, 256, 0, stream>>>(
            h, e, src, dst, wtb1, b1pe, wtb2, bb2, (void*)enew, estats);
        bn_finalize_kernel<<<1, 128, 0, stream>>>(estats, gb, beb, 1.0f / NE);
        apply_gather_kernel<0><<<(NN + 3) / 4, 256, 0, stream>>>(
            e, estats, ioff, icsr, nullptr, enew, agg);
    }

    // ---- atom (node) path ----
    mlp_mfma_kernel<1, 0><<<(NN + 63) / 64, 256, 0, stream>>>(
        h, agg, nullptr, nullptr, wta1, b1pn, wta2, ba2, (void*)hnew, nstats);
    bn_finalize_kernel<<<1, 128, 0, stream>>>(nstats, ga, bea, 1.0f / NN);
    node_apply_kernel<<<(NN * 32) / 256, 256, 0, stream>>>(h, nstats, hnew);
}